// Round 1
// 728.011 us; speedup vs baseline: 1.0160x; 1.0160x over previous
//
#include <hip/hip_runtime.h>
#include <hip/hip_bf16.h>
#include <stdint.h>

// Set Transformer forward on gfx950. Round 4.
// Changes vs R3: launch-count reduction (31 -> 22 dispatches):
//   - k_convert + k_emb + k_sbuild fused into one k_prep launch
//   - per-layer QK-proj + V^T-proj fused into one multi-job GEMM launch
//   - PMA pq+pk+pv fused into one multi-job GEMM launch
// Flash VALU trim: softmax scale folded into K-projection epilogue (K only
// feeds QK^T; residual path uses Q, so k_combine is untouched); manual RNE
// bit-math replaced with scalar bf16 cast (compiler pairs into cvt_pk).

#define HID 512
#define EMBD 768
#define NCTX 2048
#define HD 64

typedef __attribute__((ext_vector_type(8))) short v8s;   // 8 x bf16
typedef __attribute__((ext_vector_type(4))) float v4f;   // MFMA accumulator

#define MFMA(a, b, c) __builtin_amdgcn_mfma_f32_16x16x32_bf16((a), (b), (c), 0, 0, 0)

__device__ __forceinline__ short f2bf(float f) {
  return __builtin_bit_cast(short, __float2bfloat16(f));
}
__device__ __forceinline__ float bf2f(short s) {
  uint32_t u = ((uint32_t)(uint16_t)s) << 16;
  return __builtin_bit_cast(float, u);
}
__device__ __forceinline__ v8s ldbf8(const short* p) { return *(const v8s*)p; }

// ---------------- fused prep: weight convert + embedding + S build ----------
struct ConvDesc {
  const float* src[20];
  unsigned cum[21];
};

#define NB_CONV 22016u   // 5636096 / 256
#define NB_EMB 6144u     // 2048*768 / 256
#define NB_S 128u        // 64*512 / 256

__global__ __launch_bounds__(256) void k_prep(
    ConvDesc d, short* __restrict__ Wdst,
    const int* __restrict__ is_cat, const int* __restrict__ cat_idx,
    const int* __restrict__ reg_idx, const float* __restrict__ reg_values,
    const float* __restrict__ cat_table, const float* __restrict__ reg_table,
    const float* __restrict__ reg_W, const float* __restrict__ reg_b,
    short* __restrict__ emb_out, const float* __restrict__ S,
    short* __restrict__ s_out) {
  unsigned b = blockIdx.x;
  if (b < NB_CONV) {
    unsigned i = b * 256u + threadIdx.x;
    if (i >= d.cum[20]) return;
    int t = 0;
    while (i >= d.cum[t + 1]) ++t;
    Wdst[i] = f2bf(d.src[t][i - d.cum[t]]);
  } else if (b < NB_CONV + NB_EMB) {
    int i = (int)(b - NB_CONV) * 256 + threadIdx.x;
    int n = i / EMBD, e = i - n * EMBD;
    float v;
    if (is_cat[n]) {
      v = cat_table[(long)cat_idx[n] * EMBD + e];
    } else {
      int r = reg_idx[n];
      if (e < 512) v = reg_table[r * 512 + e];
      else {
        int e2 = e - 512;
        v = reg_W[r * 256 + e2] * reg_values[n] + reg_b[r * 256 + e2];
      }
    }
    emb_out[i] = f2bf(v);
  } else {
    int i = (int)(b - NB_CONV - NB_EMB) * 256 + threadIdx.x;
    int row = i >> 9;
    s_out[i] = (row < 7) ? f2bf(S[i]) : (short)0;
  }
}

// ---------------- multi-job NT GEMM: C[M,N] = A[M,K] @ B[N,K]^T -------------
// Up to 3 independent GEMMs in one launch; blocks decode their job from a
// base offset. One wave per 32x64 tile (as R3's k_gemm).
// epi 0: out = (acc + (col<512 ? biasA[col] : biasB[col-512])) * (col<512?sA:sB)
// epi 1: out = acc + biasA[row]
struct GemmJob {
  const short* A;
  const short* B;
  const float* biasA;
  const float* biasB;
  short* out;
  int N, KK, epi, gx, base;
  float sA, sB;
};
struct GemmBatch {
  GemmJob j[3];
  int nj;
};

__global__ __launch_bounds__(64) void k_gemm_multi(GemmBatch gb) {
  int wg = blockIdx.x;
  int ji = 0;
  if (gb.nj > 1 && wg >= gb.j[1].base) ji = 1;
  if (gb.nj > 2 && wg >= gb.j[2].base) ji = 2;
  const GemmJob& j = gb.j[ji];
  int rel = wg - j.base;
  int bx = rel % j.gx, by = rel / j.gx;
  int l = threadIdx.x, l16 = l & 15, quad = l >> 4;
  int i0 = by * 32, n0 = bx * 64;
  const int KK = j.KK;
  const short* a0p = j.A + (i0 + l16) * KK + quad * 8;
  const short* a1p = a0p + 16 * KK;
  const short* bp = j.B + (n0 + l16) * KK + quad * 8;
  v4f acc[2][4];
  for (int g = 0; g < 2; ++g)
    for (int t = 0; t < 4; ++t) acc[g][t] = (v4f){0.f, 0.f, 0.f, 0.f};
#pragma unroll 4
  for (int k = 0; k < KK; k += 32) {
    v8s a0 = ldbf8(a0p + k);
    v8s a1 = ldbf8(a1p + k);
#pragma unroll
    for (int t = 0; t < 4; ++t) {
      v8s b = ldbf8(bp + t * 16 * KK + k);
      acc[0][t] = MFMA(a0, b, acc[0][t]);
      acc[1][t] = MFMA(a1, b, acc[1][t]);
    }
  }
  for (int g = 0; g < 2; ++g)
    for (int t = 0; t < 4; ++t) {
      int col = n0 + t * 16 + l16;
      float bc = 0.f, sc = 1.f;
      if (j.epi == 0) {
        bc = (col < 512) ? j.biasA[col] : j.biasB[col - 512];
        sc = (col < 512) ? j.sA : j.sB;
      }
      for (int r = 0; r < 4; ++r) {
        int row = i0 + g * 16 + quad * 4 + r;
        float v = acc[g][t][r];
        v = (j.epi == 0) ? (v + bc) * sc : v + j.biasA[row];
        j.out[row * j.N + col] = f2bf(v);
      }
    }
}

// ---------------- single-job GEMM with residual+relu epilogue (O-proj) ------
// out = resid + relu(acc + biasA[col])
template <int KK>
__global__ __launch_bounds__(64) void k_gemm_ff(const short* __restrict__ A,
                                               const short* __restrict__ B,
                                               const float* __restrict__ biasA,
                                               const short* __restrict__ resid,
                                               short* __restrict__ out, int N) {
  int l = threadIdx.x, l16 = l & 15, quad = l >> 4;
  int i0 = blockIdx.y * 32, n0 = blockIdx.x * 64;
  const short* a0p = A + (i0 + l16) * KK + quad * 8;
  const short* a1p = a0p + 16 * KK;
  const short* bp = B + (n0 + l16) * KK + quad * 8;
  v4f acc[2][4];
  for (int g = 0; g < 2; ++g)
    for (int t = 0; t < 4; ++t) acc[g][t] = (v4f){0.f, 0.f, 0.f, 0.f};
#pragma unroll 4
  for (int k = 0; k < KK; k += 32) {
    v8s a0 = ldbf8(a0p + k);
    v8s a1 = ldbf8(a1p + k);
#pragma unroll
    for (int t = 0; t < 4; ++t) {
      v8s b = ldbf8(bp + t * 16 * KK + k);
      acc[0][t] = MFMA(a0, b, acc[0][t]);
      acc[1][t] = MFMA(a1, b, acc[1][t]);
    }
  }
  for (int g = 0; g < 2; ++g)
    for (int t = 0; t < 4; ++t) {
      int col = n0 + t * 16 + l16;
      float bc = biasA[col];
      for (int r = 0; r < 4; ++r) {
        int row = i0 + g * 16 + quad * 4 + r;
        float v = bf2f(resid[row * N + col]) + fmaxf(acc[g][t][r] + bc, 0.f);
        out[row * N + col] = f2bf(v);
      }
    }
}

// ---------------- flash attention, split-K=4, 4 waves/block ------------------
// K is pre-scaled by log2(e)/sqrt(512) in its projection epilogue, so the
// QK^T result feeds exp2 directly. Writes UNNORMALIZED fp32 partial O and
// per-row partial denominators.
__global__ __launch_bounds__(256) void k_flash(const short* __restrict__ Q, int qstride,
                                               const short* __restrict__ Kp, int kstride,
                                               const short* __restrict__ Vt,
                                               float* __restrict__ opart,
                                               float* __restrict__ lspart) {
  __shared__ __align__(16) short Kt[64 * 64];   // XOR-swizzled 16B chunks
  __shared__ __align__(16) short Vtl[64 * 64];
  __shared__ __align__(16) short P[4][16 * 72];
  const int tid = threadIdx.x;
  const int wave = tid >> 6, l = tid & 63, l16 = l & 15, quad = l >> 4;
  const int h = blockIdx.y, D0 = h * HD;
  const int i0 = blockIdx.x * 64 + wave * 16;
  const int z = blockIdx.z, jbase = z * (NCTX / 4);

  const short* qrow = Q + (i0 + l16) * qstride + D0 + quad * 8;
  const v8s aq0 = ldbf8(qrow);
  const v8s aq1 = ldbf8(qrow + 32);

  const int sr = tid >> 2, sc0 = tid & 3, sc1 = sc0 + 4;
  const short* kg = Kp + (jbase + sr) * kstride + D0;
  const short* vg = Vt + (D0 + sr) * NCTX + jbase;
  short* kl0 = &Kt[(sr * 8 + (sc0 ^ (sr & 7))) * 8];
  short* kl1 = &Kt[(sr * 8 + (sc1 ^ (sr & 7))) * 8];
  short* vl0 = &Vtl[(sr * 8 + (sc0 ^ (sr & 7))) * 8];
  short* vl1 = &Vtl[(sr * 8 + (sc1 ^ (sr & 7))) * 8];

  v4f o[4];
  float lsum[4];
  for (int t = 0; t < 4; ++t) o[t] = (v4f){0.f, 0.f, 0.f, 0.f};
  for (int r = 0; r < 4; ++r) lsum[r] = 0.f;

  v8s pk0 = ldbf8(kg + sc0 * 8), pk1 = ldbf8(kg + sc1 * 8);
  v8s pv0 = ldbf8(vg + sc0 * 8), pv1 = ldbf8(vg + sc1 * 8);

  for (int j0 = 0; j0 < NCTX / 4; j0 += 64) {
    __syncthreads();                       // prev iter's tile reads done
    *(v8s*)kl0 = pk0; *(v8s*)kl1 = pk1;
    *(v8s*)vl0 = pv0; *(v8s*)vl1 = pv1;
    __syncthreads();                       // tiles visible
    int jn = j0 + 64;
    if (jn < NCTX / 4) {
      pk0 = ldbf8(kg + jn * kstride + sc0 * 8);
      pk1 = ldbf8(kg + jn * kstride + sc1 * 8);
      pv0 = ldbf8(vg + jn + sc0 * 8);
      pv1 = ldbf8(vg + jn + sc1 * 8);
    }
    v4f s[4];
#pragma unroll
    for (int kt = 0; kt < 4; ++kt) {
      int R = kt * 16 + l16;
      v8s kb0 = *(const v8s*)&Kt[(R * 8 + (quad ^ (R & 7))) * 8];
      v8s kb1 = *(const v8s*)&Kt[(R * 8 + ((quad + 4) ^ (R & 7))) * 8];
      v4f t0 = (v4f){0.f, 0.f, 0.f, 0.f};
      t0 = MFMA(aq0, kb0, t0);
      s[kt] = MFMA(aq1, kb1, t0);
    }
    short* pw = &P[wave][0];
#pragma unroll
    for (int kt = 0; kt < 4; ++kt)
      for (int r = 0; r < 4; ++r) {
        float p = exp2f(fminf(s[kt][r], 40.f));   // K pre-scaled by log2e/sqrt(512)
        lsum[r] += p;
        pw[(quad * 4 + r) * 72 + kt * 16 + l16] = f2bf(p);
      }
    // P is wave-private: wave-local LDS ordering is enough (no block barrier)
    asm volatile("s_waitcnt lgkmcnt(0)" ::: "memory");
    v8s pa0 = *(const v8s*)&pw[l16 * 72 + quad * 8];
    v8s pa1 = *(const v8s*)&pw[l16 * 72 + 32 + quad * 8];
#pragma unroll
    for (int t = 0; t < 4; ++t) {
      int R = t * 16 + l16;
      v8s bv0 = *(const v8s*)&Vtl[(R * 8 + (quad ^ (R & 7))) * 8];
      v8s bv1 = *(const v8s*)&Vtl[(R * 8 + ((quad + 4) ^ (R & 7))) * 8];
      o[t] = MFMA(pa0, bv0, o[t]);
      o[t] = MFMA(pa1, bv1, o[t]);
    }
  }
  for (int r = 0; r < 4; ++r) {
    lsum[r] += __shfl_xor(lsum[r], 1);
    lsum[r] += __shfl_xor(lsum[r], 2);
    lsum[r] += __shfl_xor(lsum[r], 4);
    lsum[r] += __shfl_xor(lsum[r], 8);
  }
  float* ob = opart + (size_t)z * (NCTX * HID);
  for (int t = 0; t < 4; ++t)
    for (int r = 0; r < 4; ++r)
      ob[(i0 + quad * 4 + r) * HID + D0 + t * 16 + l16] = o[t][r];
  if (l16 == 0)
    for (int r = 0; r < 4; ++r)
      lspart[z * (8 * NCTX) + h * NCTX + i0 + quad * 4 + r] = lsum[r];
}

// ---------------- combine partials: out = bf16(Qresid + (sum O_p)/(sum l_p)) --
__global__ void k_combine(const float* __restrict__ op, const float* __restrict__ ls,
                          const short* __restrict__ Qr, int qstride,
                          short* __restrict__ out) {
  const int PS = NCTX * HID;
  int i = blockIdx.x * 256 + threadIdx.x;  // M*512 threads
  int row = i >> 9, col = i & 511, h = col >> 6;
  float o = op[i] + op[i + PS] + op[i + 2 * PS] + op[i + 3 * PS];
  int li = h * NCTX + row;
  float d = ls[li] + ls[li + 8 * NCTX] + ls[li + 16 * NCTX] + ls[li + 24 * NCTX];
  out[i] = f2bf(bf2f(Qr[row * qstride + col]) + o / d);
}

// ---------------- final fc: out[j] = P[j,:] . fc_w + fc_b --------------------
__global__ __launch_bounds__(64) void k_fc(const short* __restrict__ P,
                                           const float* __restrict__ fcw,
                                           const float* __restrict__ fcb,
                                           float* __restrict__ out) {
  int j = blockIdx.x, l = threadIdx.x;
  float s = 0.f;
  int d0 = l * 8;
  for (int d = d0; d < d0 + 8; ++d) s += bf2f(P[j * HID + d]) * fcw[d];
  for (int msk = 1; msk < 64; msk <<= 1) s += __shfl_xor(s, msk);
  if (l == 0) out[j] = s + fcb[0];
}

// =============================================================================
extern "C" void kernel_launch(void* const* d_in, const int* in_sizes, int n_in,
                              void* d_out, int out_size, void* d_ws, size_t ws_size,
                              hipStream_t stream) {
  const int* is_cat = (const int*)d_in[0];
  const int* cat_idx = (const int*)d_in[1];
  const int* reg_idx = (const int*)d_in[2];
  const float* reg_values = (const float*)d_in[3];
  const float* cat_table = (const float*)d_in[4];
  const float* reg_table = (const float*)d_in[5];
  const float* reg_W = (const float*)d_in[6];
  const float* reg_b = (const float*)d_in[7];
  const float* q0_w = (const float*)d_in[8];  const float* q0_b = (const float*)d_in[9];
  const float* k0_w = (const float*)d_in[10]; const float* k0_b = (const float*)d_in[11];
  const float* v0_w = (const float*)d_in[12]; const float* v0_b = (const float*)d_in[13];
  const float* o0_w = (const float*)d_in[14]; const float* o0_b = (const float*)d_in[15];
  const float* qs_w = (const float*)d_in[16]; const float* qs_b = (const float*)d_in[17];
  const float* ks_w = (const float*)d_in[18]; const float* ks_b = (const float*)d_in[19];
  const float* vs_w = (const float*)d_in[20]; const float* vs_b = (const float*)d_in[21];
  const float* os_w = (const float*)d_in[22]; const float* os_b = (const float*)d_in[23];
  const float* S    = (const float*)d_in[24];
  const float* pq_w = (const float*)d_in[25]; const float* pq_b = (const float*)d_in[26];
  const float* pk_w = (const float*)d_in[27]; const float* pk_b = (const float*)d_in[28];
  const float* pv_w = (const float*)d_in[29]; const float* pv_b = (const float*)d_in[30];
  const float* po_w = (const float*)d_in[31]; const float* po_b = (const float*)d_in[32];
  const float* fc_w = (const float*)d_in[33]; const float* fc_b = (const float*)d_in[34];

  short* W = (short*)d_ws;

  // ---- packed bf16 weights (shorts). Per layer: [wq;wk] adjacent, wv, wo.
  const unsigned OWQK[4] = {0u, 1441792u, 2490368u, 3538944u};
  const unsigned OWV[4]  = {786432u, 1966080u, 3014656u, 4063232u};
  const unsigned OWO[4]  = {1179648u, 2228224u, 3276800u, 4325376u};
  const unsigned OPQW = 4587520u, OPKW = 4849664u, OPVW = 5111808u, OPOW = 5373952u;
  const unsigned TOTW = 5636096u;
  // ---- bf16 activations
  const unsigned OEMB = TOTW;              // 2048x768
  const unsigned OXA  = OEMB + 1572864u;   // 2048x512
  const unsigned OXB  = OXA + 1048576u;    // 2048x512
  const unsigned OQK  = OXB + 1048576u;    // 2048x1024 (Q|K fused; K pre-scaled)
  const unsigned OVT  = OQK + 2097152u;    // 512x2048 (V transposed)
  const unsigned OOH  = OVT + 1048576u;    // 2048x512 (attn out)
  const unsigned OSB  = OOH + 1048576u;    // 64x512 (S padded)
  const unsigned OQPP = OSB + 32768u;      // 64x512
  const unsigned OKPP = OQPP + 32768u;     // 2048x512
  const unsigned OOHP = OKPP + 1048576u;   // 64x512
  const unsigned OPP  = OOHP + 32768u;     // 32x512 (PMA final, padded)
  const unsigned OF32 = OPP + 32768u;      // fp32 region starts here (even)
  float* F = (float*)(W + OF32);           // opart: 4 x [2048x512] fp32
  float* LS = F + 4u * 1048576u;           // lspart: 4 x [8x2048] fp32

  const float C2 = 0.06375872f;            // log2(e)/sqrt(512), folded into K

  // ---- fused prep: weight conversion + embedding + S build ----
  ConvDesc cd;
  const float* srcs[20] = {
      q0_w, k0_w, v0_w, o0_w,
      qs_w, ks_w, vs_w, os_w,
      qs_w + 262144, ks_w + 262144, vs_w + 262144, os_w + 262144,
      qs_w + 524288, ks_w + 524288, vs_w + 524288, os_w + 524288,
      pq_w, pk_w, pv_w, po_w};
  const unsigned cums[21] = {0u,       393216u,  786432u,  1179648u, 1441792u,
                             1703936u, 1966080u, 2228224u, 2490368u, 2752512u,
                             3014656u, 3276800u, 3538944u, 3801088u, 4063232u,
                             4325376u, 4587520u, 4849664u, 5111808u, 5373952u,
                             5636096u};
  for (int i = 0; i < 20; ++i) cd.src[i] = srcs[i];
  for (int i = 0; i < 21; ++i) cd.cum[i] = cums[i];
  k_prep<<<NB_CONV + NB_EMB + NB_S, 256, 0, stream>>>(
      cd, W, is_cat, cat_idx, reg_idx, reg_values, cat_table, reg_table,
      reg_W, reg_b, W + OEMB, S, W + OSB);

  const float* bq[4] = {q0_b, qs_b, qs_b + 512, qs_b + 1024};
  const float* bk[4] = {k0_b, ks_b, ks_b + 512, ks_b + 1024};
  const float* bv[4] = {v0_b, vs_b, vs_b + 512, vs_b + 1024};
  const float* bo[4] = {o0_b, os_b, os_b + 512, os_b + 1024};
  const unsigned oxin[4]  = {OEMB, OXA, OXB, OXA};
  const unsigned oxout[4] = {OXA, OXB, OXA, OXB};

  dim3 gf(32, 8, 4);  // flash: 32 q-blocks x 8 heads x 4 key-chunks

  for (int l = 0; l < 4; ++l) {
    const short* X = W + oxin[l];
    short* Xout = W + oxout[l];
    int KKl = (l == 0) ? 768 : 512;
    // fused QK-projection (K scaled by C2) + V^T production: one launch
    GemmBatch gb{};
    gb.nj = 2;
    gb.j[0] = {X, W + OWQK[l], bq[l], bk[l], W + OQK, 1024, KKl, 0, 16, 0, 1.f, C2};
    gb.j[1] = {W + OWV[l], X, bv[l], nullptr, W + OVT, 2048, KKl, 1, 32, 1024, 1.f, 1.f};
    k_gemm_multi<<<1536, 64, 0, stream>>>(gb);
    k_flash<<<gf, 256, 0, stream>>>(W + OQK, 1024, W + OQK + 512, 1024, W + OVT, F, LS);
    k_combine<<<(2048 * 512) / 256, 256, 0, stream>>>(F, LS, W + OQK, 1024, W + OOH);
    k_gemm_ff<512><<<dim3(8, 64), 64, 0, stream>>>(W + OOH, W + OWO[l], bo[l], W + OOH, Xout, 512);
  }

  // ---- PMA decoder ----
  // fused pq + pk (scaled by C2) + pv projections: one launch
  GemmBatch gp{};
  gp.nj = 3;
  gp.j[0] = {W + OSB, W + OPQW, pq_b, pq_b, W + OQPP, 512, 512, 0, 8, 0, 1.f, 1.f};
  gp.j[1] = {W + OXB, W + OPKW, pk_b, pk_b, W + OKPP, 512, 512, 0, 8, 16, C2, C2};
  gp.j[2] = {W + OPVW, W + OXB, pv_b, nullptr, W + OVT, 2048, 512, 1, 32, 528, 1.f, 1.f};
  k_gemm_multi<<<1040, 64, 0, stream>>>(gp);
  k_flash<<<dim3(1, 8, 4), 256, 0, stream>>>(W + OQPP, 512, W + OKPP, 512, W + OVT, F, LS);
  k_combine<<<(16 * 512) / 256, 256, 0, stream>>>(F, LS, W + OQPP, 512, W + OOHP);
  k_gemm_ff<512><<<dim3(8, 1), 64, 0, stream>>>(W + OOHP, W + OPOW, po_b, W + OOHP, W + OPP, 512);
  k_fc<<<7, 64, 0, stream>>>(W + OPP, fc_w, fc_b, (float*)d_out);
}